// Round 2
// baseline (5501.574 us; speedup 1.0000x reference)
//
#include <hip/hip_runtime.h>
#include <hip/hip_bf16.h>

// ---------------------------------------------------------------------------
// RETRO-ish transformer forward, MI355X gfx950.
// Round 2: same algorithm as round 1, workspace compacted 152MB -> 72MB
// (suspected container kill = d_ws overflow). bf16 MFMA GEMMs, fp32 VALU
// flash attention, fp32 LN/rope/softmax. CCA e/ck/cv stored bf16 + aliased.
//   B=2 S=1024 D=1024 H=16 DK=64 L=6 CL=64 V=32000 DFF=4096
//   CHUNKS=16 NEIGH=2 NLEN=128 CA_LAYER=3
// ---------------------------------------------------------------------------

#define MEG 1048576

using bf16x8 = __attribute__((ext_vector_type(8))) short;
using f32x4  = __attribute__((ext_vector_type(4))) float;

__device__ __forceinline__ unsigned short f2bf(float f) {
    unsigned int u = __float_as_uint(f);
    u += 0x7fffu + ((u >> 16) & 1u);          // round-to-nearest-even
    return (unsigned short)(u >> 16);
}
__device__ __forceinline__ float bf2f(unsigned short b) {
    return __uint_as_float((unsigned int)b << 16);
}

// ---------------------------------------------------------------------------
// Embedding gather: h[row][:] = emb[x[row]][:]   (rows = B*S = 2048)
// ---------------------------------------------------------------------------
__global__ __launch_bounds__(256) void embed_k(const float* __restrict__ emb,
                                               const int* __restrict__ x,
                                               float* __restrict__ h) {
    int row = blockIdx.x;
    int d = threadIdx.x * 4;
    size_t src = (size_t)x[row] * 1024 + d;
    *(float4*)&h[(size_t)row * 1024 + d] = *(const float4*)&emb[src];
}

// ---------------------------------------------------------------------------
// LayerNorm over D=1024. One block per row, 256 threads, 4 floats/thread.
// mode 0: dst[row] = LN(src[row])
// mode 1: dst[row] = LN(src[gidx[row]])          (gather, for ret_emb)
// mode 2: CCA prep: row=(b,r); r<961 -> LN(h[b][63+r]); else zeros
// obf16: write dst as bf16 (ushort) instead of fp32
// ---------------------------------------------------------------------------
__device__ __forceinline__ float block_sum(float v, float* red) {
    #pragma unroll
    for (int off = 32; off >= 1; off >>= 1) v += __shfl_xor(v, off);
    int w = threadIdx.x >> 6;
    __syncthreads();
    if ((threadIdx.x & 63) == 0) red[w] = v;
    __syncthreads();
    return red[0] + red[1] + red[2] + red[3];
}

__global__ __launch_bounds__(256) void ln_k(const float* __restrict__ src,
                                            void* __restrict__ dstv,
                                            const float* __restrict__ sc,
                                            const float* __restrict__ bi,
                                            const int* __restrict__ gidx,
                                            int mode, int obf16) {
    __shared__ float red[8];
    int row = blockIdx.x;
    int d = threadIdx.x * 4;
    const float* srow;
    if (mode == 0) {
        srow = src + (size_t)row * 1024;
    } else if (mode == 1) {
        srow = src + (size_t)gidx[row] * 1024;
    } else {
        int b = row >> 10, r = row & 1023;
        if (r >= 961) {                         // padded query rows -> zeros
            if (obf16) {
                uint2 z = {0u, 0u};
                *(uint2*)&((unsigned short*)dstv)[(size_t)row * 1024 + d] = z;
            } else {
                float4 z = {0.f, 0.f, 0.f, 0.f};
                *(float4*)&((float*)dstv)[(size_t)row * 1024 + d] = z;
            }
            return;
        }
        srow = src + (size_t)(b * 1024 + 63 + r) * 1024;
    }
    float4 xv = *(const float4*)&srow[d];
    float s = block_sum(xv.x + xv.y + xv.z + xv.w, red);
    float mu = s * (1.f / 1024.f);
    float d0 = xv.x - mu, d1 = xv.y - mu, d2 = xv.z - mu, d3 = xv.w - mu;
    float s2 = block_sum(d0*d0 + d1*d1 + d2*d2 + d3*d3, red);
    float rs = 1.0f / sqrtf(s2 * (1.f / 1024.f) + 1e-5f);
    float4 sv = *(const float4*)&sc[d];
    float4 bv = *(const float4*)&bi[d];
    float4 o = { d0*rs*sv.x + bv.x, d1*rs*sv.y + bv.y,
                 d2*rs*sv.z + bv.z, d3*rs*sv.w + bv.w };
    if (obf16) {
        uint2 pk = { (unsigned)f2bf(o.x) | ((unsigned)f2bf(o.y) << 16),
                     (unsigned)f2bf(o.z) | ((unsigned)f2bf(o.w) << 16) };
        *(uint2*)&((unsigned short*)dstv)[(size_t)row * 1024 + d] = pk;
    } else {
        *(float4*)&((float*)dstv)[(size_t)row * 1024 + d] = o;
    }
}

// ---------------------------------------------------------------------------
// Generic bf16 MFMA GEMM: C[M,N] = A[M,K] @ B[K,N] + bias (+res) (+relu)
// A fp32 (converted RNE->bf16 in staging) or bf16 (a_bf16). B fp32 weights.
// C fp32 or bf16 (c_bf16). Tile 128x128, BK=32, 4 waves, 64x64 per wave.
// grid.z selects among up to 3 (B,bias,C) triples (QKV batched in 1 launch).
// LDS: A row-major [128][40] bf16, B fragment-ordered [nt][lane][8].
// ---------------------------------------------------------------------------
struct GemmArgs {
    const void*  A;
    const float* B[3];
    const float* bias[3];
    void*        C[3];
    const float* res;     // residual added to output (nullptr = none, fp32 only)
    int M, N, K;
    int relu, a_bf16, c_bf16;
};

__global__ __launch_bounds__(256) void gemm_k(GemmArgs g) {
    const int z = blockIdx.z;
    const float* __restrict__ Bw   = g.B[z];
    const float* __restrict__ bias = g.bias[z];
    const int N = g.N, K = g.K;
    const int m0 = blockIdx.x * 128, n0 = blockIdx.y * 128;

    __shared__ __align__(16) short lA[128 * 40];
    __shared__ __align__(16) short lB[4096];     // [nt(8)][lane(64)][j(8)]

    const int tid = threadIdx.x, wave = tid >> 6, lane = tid & 63;
    const int wm = (wave >> 1) * 64, wn = (wave & 1) * 64;

    f32x4 acc[4][4];
    f32x4 zero = {0.f, 0.f, 0.f, 0.f};
    #pragma unroll
    for (int i = 0; i < 4; i++)
        #pragma unroll
        for (int j = 0; j < 4; j++) acc[i][j] = zero;

    for (int k0 = 0; k0 < K; k0 += 32) {
        __syncthreads();
        // ---- stage A: 128x32 -> bf16 LDS
        if (g.a_bf16) {
            const unsigned short* A16 = (const unsigned short*)g.A;
            #pragma unroll
            for (int i = 0; i < 2; i++) {
                int j = i * 256 + tid;           // 0..511
                int m = j >> 2, k8 = (j & 3) * 8;
                uint4 av = *(const uint4*)(A16 + (size_t)(m0 + m) * K + k0 + k8);
                *(uint4*)&lA[m * 40 + k8] = av;
            }
        } else {
            const float* A = (const float*)g.A;
            #pragma unroll
            for (int i = 0; i < 4; i++) {
                int j = i * 256 + tid;           // 0..1023
                int m = j >> 3, k4 = (j & 7) * 4;
                const float4 av = *(const float4*)(A + (size_t)(m0 + m) * K + k0 + k4);
                unsigned int lo = (unsigned)f2bf(av.x) | ((unsigned)f2bf(av.y) << 16);
                unsigned int hi = (unsigned)f2bf(av.z) | ((unsigned)f2bf(av.w) << 16);
                uint2 pk = {lo, hi};
                *(uint2*)&lA[m * 40 + k4] = pk;
            }
        }
        // ---- stage B: 32x128 -> fragment order. 2 tasks/thread,
        //      each task: 8 k-strided scalar loads (coalesced in n), 1 b128 write.
        #pragma unroll
        for (int i = 0; i < 2; i++) {
            int task = i * 256 + tid;            // 0..511
            int nn = task & 127, kq = task >> 7; // kq 0..3
            const float* bp = Bw + (size_t)(k0 + kq * 8) * N + n0 + nn;
            unsigned int t0 = f2bf(bp[0]);
            unsigned int t1 = f2bf(bp[(size_t)1 * N]);
            unsigned int t2 = f2bf(bp[(size_t)2 * N]);
            unsigned int t3 = f2bf(bp[(size_t)3 * N]);
            unsigned int t4 = f2bf(bp[(size_t)4 * N]);
            unsigned int t5 = f2bf(bp[(size_t)5 * N]);
            unsigned int t6 = f2bf(bp[(size_t)6 * N]);
            unsigned int t7 = f2bf(bp[(size_t)7 * N]);
            uint4 pk = { t0 | (t1 << 16), t2 | (t3 << 16),
                         t4 | (t5 << 16), t6 | (t7 << 16) };
            int ln = (kq << 4) | (nn & 15);
            *(uint4*)&lB[((nn >> 4) * 64 + ln) * 8] = pk;
        }
        __syncthreads();
        // ---- compute: 8 ds_read_b128 + 16 MFMA
        bf16x8 af[4], bfg[4];
        #pragma unroll
        for (int mi = 0; mi < 4; mi++)
            af[mi] = *(bf16x8*)&lA[(wm + mi * 16 + (lane & 15)) * 40 + (lane >> 4) * 8];
        #pragma unroll
        for (int ni = 0; ni < 4; ni++)
            bfg[ni] = *(bf16x8*)&lB[(((wn >> 4) + ni) * 64 + lane) * 8];
        #pragma unroll
        for (int mi = 0; mi < 4; mi++)
            #pragma unroll
            for (int ni = 0; ni < 4; ni++)
                acc[mi][ni] = __builtin_amdgcn_mfma_f32_16x16x32_bf16(
                    af[mi], bfg[ni], acc[mi][ni], 0, 0, 0);
    }
    // ---- epilogue: C/D layout col=lane&15, row=(lane>>4)*4+r  (m89-verified)
    const int r0 = m0 + wm + (lane >> 4) * 4;
    const int c0 = n0 + wn + (lane & 15);
    #pragma unroll
    for (int ni = 0; ni < 4; ni++) {
        int col = c0 + ni * 16;
        float bb = bias[col];
        #pragma unroll
        for (int mi = 0; mi < 4; mi++) {
            #pragma unroll
            for (int r = 0; r < 4; r++) {
                int row = r0 + mi * 16 + r;
                float val = acc[mi][ni][r] + bb;
                if (g.relu) val = fmaxf(val, 0.f);
                if (g.c_bf16) {
                    ((unsigned short*)g.C[z])[(size_t)row * N + col] = f2bf(val);
                } else {
                    if (g.res) val += g.res[(size_t)row * N + col];
                    ((float*)g.C[z])[(size_t)row * N + col] = val;
                }
            }
        }
    }
}

// ---------------------------------------------------------------------------
// RoPE in-place on q and k. (B,S,H,DK) pairs (d, d+32), half=32.
// grid: (4096, 2) x 256 threads. blockIdx.y: 0 -> q, 1 -> k.
// ---------------------------------------------------------------------------
__global__ __launch_bounds__(256) void rope_k(float* __restrict__ q,
                                              float* __restrict__ k) {
    int idx = blockIdx.x * 256 + threadIdx.x;   // 0..1048575
    float* p = blockIdx.y ? k : q;
    int d    = idx & 31;
    int head = (idx >> 5) & 15;
    int i    = (idx >> 9) & 1023;
    int b    = idx >> 19;
    size_t base = ((size_t)(b * 1024 + i)) * 1024 + head * 64 + d;
    float x1 = p[base], x2 = p[base + 32];
    float th = __expf(-0.28782313662425575f * (float)d);  // ln(10000)/32
    float fr = (float)i * th;
    float s, c;
    sincosf(fr, &s, &c);
    p[base]      = x1 * c - x2 * s;
    p[base + 32] = x1 * s + x2 * c;
}

// ---------------------------------------------------------------------------
// Causal self-attention, flash-style, fp32 VALU. One block = (b,head, 64-query
// tile). 4 waves x 16 rows each. Keys streamed in 64-chunks with online
// softmax. K LDS is rotation-swizzled (slot j*64 + ((d+j)&63)) for
// conflict-free column reads. Output: h += softmax(QK^T/8) V   (residual).
// ---------------------------------------------------------------------------
__global__ __launch_bounds__(256) void attn_causal(const float* __restrict__ q,
                                                   const float* __restrict__ kk,
                                                   const float* __restrict__ vv,
                                                   float* __restrict__ h) {
    __shared__ __align__(16) float Qs[64 * 64];
    __shared__ __align__(16) float Ks[64 * 64];
    __shared__ __align__(16) float Vs[64 * 64];
    __shared__ __align__(16) float Ps[64 * 64];
    const int b = blockIdx.x >> 4, hd = blockIdx.x & 15, qt = blockIdx.y;
    const int tid = threadIdx.x, wave = tid >> 6, lane = tid & 63;
    const int w16 = wave * 16;
    const size_t qbase = ((size_t)(b * 1024 + qt * 64)) * 1024 + hd * 64;

    #pragma unroll
    for (int e = 0; e < 16; e++) {
        int elem = e * 256 + tid;
        int r = elem >> 6, d = elem & 63;
        Qs[r * 64 + d] = q[qbase + (size_t)r * 1024 + d] * 0.125f;
    }
    float acc[16], O[16], mrow[16], lrow[16];
    #pragma unroll
    for (int i = 0; i < 16; i++) { O[i] = 0.f; mrow[i] = -INFINITY; lrow[i] = 0.f; }

    for (int kt = 0; kt <= qt; kt++) {
        __syncthreads();
        size_t kbase = ((size_t)(b * 1024 + kt * 64)) * 1024 + hd * 64;
        #pragma unroll
        for (int e = 0; e < 16; e++) {
            int elem = e * 256 + tid;
            int r = elem >> 6, d = elem & 63;
            float kvv = kk[kbase + (size_t)r * 1024 + d];
            Ks[r * 64 + ((d + r) & 63)] = kvv;        // rotation swizzle
            Vs[r * 64 + d] = vv[kbase + (size_t)r * 1024 + d];
        }
        __syncthreads();
        // scores: lane = key j
        #pragma unroll
        for (int i = 0; i < 16; i++) acc[i] = 0.f;
        #pragma unroll 4
        for (int d4 = 0; d4 < 16; d4++) {
            float k0 = Ks[lane * 64 + ((4 * d4 + 0 + lane) & 63)];
            float k1 = Ks[lane * 64 + ((4 * d4 + 1 + lane) & 63)];
            float k2 = Ks[lane * 64 + ((4 * d4 + 2 + lane) & 63)];
            float k3 = Ks[lane * 64 + ((4 * d4 + 3 + lane) & 63)];
            #pragma unroll
            for (int rr = 0; rr < 16; rr++) {
                float4 qv = *(float4*)&Qs[(w16 + rr) * 64 + 4 * d4];
                acc[rr] += qv.x * k0 + qv.y * k1 + qv.z * k2 + qv.w * k3;
            }
        }
        // online softmax update
        bool diag = (kt == qt);
        #pragma unroll
        for (int rr = 0; rr < 16; rr++) {
            float s = acc[rr];
            if (diag && lane > (w16 + rr)) s = -INFINITY;
            float mx = s;
            #pragma unroll
            for (int off = 32; off >= 1; off >>= 1) mx = fmaxf(mx, __shfl_xor(mx, off));
            float mn = fmaxf(mrow[rr], mx);
            float alpha = __expf(mrow[rr] - mn);
            float pp = __expf(s - mn);
            float ps = pp;
            #pragma unroll
            for (int off = 32; off >= 1; off >>= 1) ps += __shfl_xor(ps, off);
            lrow[rr] = lrow[rr] * alpha + ps;
            mrow[rr] = mn;
            O[rr] *= alpha;
            Ps[(w16 + rr) * 64 + lane] = pp;          // wave-private rows
        }
        // PV: lane = dim d
        #pragma unroll 4
        for (int j4 = 0; j4 < 16; j4++) {
            float v0 = Vs[(4 * j4 + 0) * 64 + lane];
            float v1 = Vs[(4 * j4 + 1) * 64 + lane];
            float v2 = Vs[(4 * j4 + 2) * 64 + lane];
            float v3 = Vs[(4 * j4 + 3) * 64 + lane];
            #pragma unroll
            for (int rr = 0; rr < 16; rr++) {
                float4 pv = *(float4*)&Ps[(w16 + rr) * 64 + 4 * j4];
                O[rr] += pv.x * v0 + pv.y * v1 + pv.z * v2 + pv.w * v3;
            }
        }
    }
    #pragma unroll
    for (int rr = 0; rr < 16; rr++) {
        size_t idx = qbase + (size_t)(w16 + rr) * 1024 + lane;
        h[idx] += O[rr] / lrow[rr];                   // residual add
    }
}

// ---------------------------------------------------------------------------
// Chunked cross-attention core. block = (b*16+c, head). 64 queries (CL),
// 256 keys (NEIGH*NLEN) in 4 chunks, no mask. K/V in bf16. Store to out.
// ---------------------------------------------------------------------------
__global__ __launch_bounds__(256) void attn_cca(const float* __restrict__ q,
                                                const unsigned short* __restrict__ kk,
                                                const unsigned short* __restrict__ vv,
                                                float* __restrict__ out) {
    __shared__ __align__(16) float Qs[64 * 64];
    __shared__ __align__(16) float Ks[64 * 64];
    __shared__ __align__(16) float Vs[64 * 64];
    __shared__ __align__(16) float Ps[64 * 64];
    const int bc = blockIdx.x, hd = blockIdx.y;
    const int b = bc >> 4, c = bc & 15;
    const int tid = threadIdx.x, wave = tid >> 6, lane = tid & 63;
    const int w16 = wave * 16;
    const size_t qbase = ((size_t)(b * 1024 + c * 64)) * 1024 + hd * 64;
    const size_t kbase0 = ((size_t)(bc * 256)) * 1024 + hd * 64;

    #pragma unroll
    for (int e = 0; e < 16; e++) {
        int elem = e * 256 + tid;
        int r = elem >> 6, d = elem & 63;
        Qs[r * 64 + d] = q[qbase + (size_t)r * 1024 + d] * 0.125f;
    }
    float acc[16], O[16], mrow[16], lrow[16];
    #pragma unroll
    for (int i = 0; i < 16; i++) { O[i] = 0.f; mrow[i] = -INFINITY; lrow[i] = 0.f; }

    for (int kt = 0; kt < 4; kt++) {
        __syncthreads();
        size_t kbase = kbase0 + (size_t)(kt * 64) * 1024;
        #pragma unroll
        for (int e = 0; e < 16; e++) {
            int elem = e * 256 + tid;
            int r = elem >> 6, d = elem & 63;
            Ks[r * 64 + ((d + r) & 63)] = bf2f(kk[kbase + (size_t)r * 1024 + d]);
            Vs[r * 64 + d] = bf2f(vv[kbase + (size_t)r * 1024 + d]);
        }
        __syncthreads();
        #pragma unroll
        for (int i = 0; i < 16; i++) acc[i] = 0.f;
        #pragma unroll 4
        for (int d4 = 0; d4 < 16; d4++) {
            float k0 = Ks[lane * 64 + ((4 * d4 + 0 + lane) & 63)];
            float k1 = Ks[lane * 64 + ((4 * d4 + 1 + lane) & 63)];
            float k2 = Ks[lane * 64 + ((4 * d4 + 2 + lane) & 63)];
            float k3 = Ks[lane * 64 + ((4 * d4 + 3 + lane) & 63)];
            #pragma unroll
            for (int rr = 0; rr < 16; rr++) {
                float4 qv = *(float4*)&Qs[(w16 + rr) * 64 + 4 * d4];
                acc[rr] += qv.x * k0 + qv.y * k1 + qv.z * k2 + qv.w * k3;
            }
        }
        #pragma unroll
        for (int rr = 0; rr < 16; rr++) {
            float s = acc[rr];
            float mx = s;
            #pragma unroll
            for (int off = 32; off >= 1; off >>= 1) mx = fmaxf(mx, __shfl_xor(mx, off));
            float mn = fmaxf(mrow[rr], mx);
            float alpha = __expf(mrow[rr] - mn);
            float pp = __expf(s - mn);
            float ps = pp;
            #pragma unroll
            for (int off = 32; off >= 1; off >>= 1) ps += __shfl_xor(ps, off);
            lrow[rr] = lrow[rr] * alpha + ps;
            mrow[rr] = mn;
            O[rr] *= alpha;
            Ps[(w16 + rr) * 64 + lane] = pp;
        }
        #pragma unroll 4
        for (int j4 = 0; j4 < 16; j4++) {
            float v0 = Vs[(4 * j4 + 0) * 64 + lane];
            float v1 = Vs[(4 * j4 + 1) * 64 + lane];
            float v2 = Vs[(4 * j4 + 2) * 64 + lane];
            float v3 = Vs[(4 * j4 + 3) * 64 + lane];
            #pragma unroll
            for (int rr = 0; rr < 16; rr++) {
                float4 pv = *(float4*)&Ps[(w16 + rr) * 64 + 4 * j4];
                O[rr] += pv.x * v0 + pv.y * v1 + pv.z * v2 + pv.w * v3;
            }
        }
    }
    #pragma unroll
    for (int rr = 0; rr < 16; rr++) {
        size_t idx = qbase + (size_t)(w16 + rr) * 1024 + lane;
        out[idx] = O[rr] / lrow[rr];
    }
}

// ---------------------------------------------------------------------------
// CCA shift-add: h[b][63+r] += src[b][r] for r in 0..960
// ---------------------------------------------------------------------------
__global__ __launch_bounds__(256) void add_shift_k(const float* __restrict__ src,
                                                   float* __restrict__ h) {
    int row = blockIdx.x;              // 0..1921
    int b = row / 961, r = row % 961;
    int d = threadIdx.x * 4;
    size_t s = ((size_t)(b * 1024 + r)) * 1024 + d;
    size_t dst = ((size_t)(b * 1024 + 63 + r)) * 1024 + d;
    float4 a = *(const float4*)&src[s];
    float4 o = *(float4*)&h[dst];
    o.x += a.x; o.y += a.y; o.z += a.z; o.w += a.w;
    *(float4*)&h[dst] = o;
}

// ---------------------------------------------------------------------------
// Host orchestration
// ---------------------------------------------------------------------------
static void gemm(hipStream_t s, const void* A,
                 const float* B0, const float* B1, const float* B2,
                 const float* bi0, const float* bi1, const float* bi2,
                 void* C0, void* C1, void* C2, const float* res,
                 int M, int N, int K, int relu, int a_bf16, int c_bf16, int z) {
    GemmArgs ga;
    ga.A = A;
    ga.B[0] = B0; ga.B[1] = B1; ga.B[2] = B2;
    ga.bias[0] = bi0; ga.bias[1] = bi1; ga.bias[2] = bi2;
    ga.C[0] = C0; ga.C[1] = C1; ga.C[2] = C2;
    ga.res = res; ga.M = M; ga.N = N; ga.K = K;
    ga.relu = relu; ga.a_bf16 = a_bf16; ga.c_bf16 = c_bf16;
    gemm_k<<<dim3(M / 128, N / 128, z), 256, 0, s>>>(ga);
}

extern "C" void kernel_launch(void* const* d_in, const int* in_sizes, int n_in,
                              void* d_out, int out_size, void* d_ws, size_t ws_size,
                              hipStream_t stream) {
    (void)in_sizes; (void)n_in; (void)out_size; (void)ws_size;
    const float* emb     = (const float*)d_in[0];
    const float* sa_ln_s = (const float*)d_in[1];
    const float* sa_ln_b = (const float*)d_in[2];
    const float* Wq      = (const float*)d_in[3];
    const float* Wk      = (const float*)d_in[4];
    const float* Wv      = (const float*)d_in[5];
    const float* bq      = (const float*)d_in[6];
    const float* bk      = (const float*)d_in[7];
    const float* bv      = (const float*)d_in[8];
    const float* ff_ln_s = (const float*)d_in[9];
    const float* ff_ln_b = (const float*)d_in[10];
    const float* W1      = (const float*)d_in[11];
    const float* b1      = (const float*)d_in[12];
    const float* W2      = (const float*)d_in[13];
    const float* b2      = (const float*)d_in[14];
    const float* cln_s   = (const float*)d_in[15];
    const float* cln_b   = (const float*)d_in[16];
    const float* cWq     = (const float*)d_in[17];
    const float* cWk     = (const float*)d_in[18];
    const float* cWv     = (const float*)d_in[19];
    const float* cbq     = (const float*)d_in[20];
    const float* cbk     = (const float*)d_in[21];
    const float* cbv     = (const float*)d_in[22];
    const float* cWo     = (const float*)d_in[23];
    const float* cbo     = (const float*)d_in[24];
    const float* ne_s    = (const float*)d_in[25];
    const float* ne_b    = (const float*)d_in[26];
    const float* Wr      = (const float*)d_in[27];
    const float* br      = (const float*)d_in[28];
    const int*   x       = (const int*)d_in[29];
    const int*   ret     = (const int*)d_in[30];
    float* out = (float*)d_out;
    float* ws  = (float*)d_ws;

    // -----------------------------------------------------------------------
    // Workspace layout (units of MEG floats). PEAK USE = 18 MEG = 72 MB.
    //   h   : 0..2     residual stream
    //   hn  : 2..4     LN output        (CCA: also attention output)
    //   qb  : 4..6     Q                (CCA: also proj output)
    //   kb  : 6..8     K
    //   vb  : 8..10    V
    //   ffh : 4..12    FFW hidden (aliases qb..vb + 10..12; FFW only)
    //   e16 : bf16 @ 6..10   LN(ret_emb), 8192x1024 (aliases kb,vb; CCA only)
    //   ck16: bf16 @ 10..14  K_cca (CCA only, dead before FFW)
    //   cv16: bf16 @ 14..18  V_cca (CCA only)
    // All aliases have disjoint lifetimes (CCA completes before layer-3 FFW).
    // -----------------------------------------------------------------------
    float* h   = ws;
    float* hn  = ws + 2 * MEG;
    float* qb  = ws + 4 * MEG;
    float* kb  = ws + 6 * MEG;
    float* vb  = ws + 8 * MEG;
    float* ffh = ws + 4 * MEG;
    unsigned short* e16  = (unsigned short*)(ws + 6 * MEG);
    unsigned short* ck16 = (unsigned short*)(ws + 10 * MEG);
    unsigned short* cv16 = (unsigned short*)(ws + 14 * MEG);

    embed_k<<<2048, 256, 0, stream>>>(emb, x, h);

    for (int p = 0; p < 6; p++) {
        // ---- self attention ----
        ln_k<<<2048, 256, 0, stream>>>(h, hn, sa_ln_s + p * 1024, sa_ln_b + p * 1024,
                                       nullptr, 0, 0);
        gemm(stream, hn,
             Wq + (size_t)p * MEG, Wk + (size_t)p * MEG, Wv + (size_t)p * MEG,
             bq + p * 1024, bk + p * 1024, bv + p * 1024,
             qb, kb, vb, nullptr, 2048, 1024, 1024, 0, 0, 0, 3);
        rope_k<<<dim3(4096, 2), 256, 0, stream>>>(qb, kb);
        attn_causal<<<dim3(32, 16), 256, 0, stream>>>(qb, kb, vb, h);

        // ---- chunked cross attention at layer 3 ----
        if (p == 3) {
            // e = LN(emb[ret]) -> bf16        (e16 aliases kb,vb)
            ln_k<<<8192, 256, 0, stream>>>(emb, e16, ne_s, ne_b, ret, 1, 1);
            // K,V = e @ cWk/cWv + b -> bf16   (one launch, grid.z=2)
            gemm(stream, e16, cWk, cWv, cWv, cbk, cbv, cbv,
                 ck16, cv16, cv16, nullptr, 8192, 1024, 1024, 0, 1, 1, 2);
            // e16 dead from here; hn/qb reusable
            ln_k<<<2048, 256, 0, stream>>>(h, hn, cln_s, cln_b, nullptr, 2, 0);
            gemm(stream, hn, cWq, cWq, cWq, cbq, cbq, cbq,
                 qb, qb, qb, nullptr, 2048, 1024, 1024, 0, 0, 0, 1);
            // attention out -> hn (hn free after q-gemm)
            attn_cca<<<dim3(32, 16), 256, 0, stream>>>(qb, ck16, cv16, hn);
            // proj out -> qb (qb free after attention)
            gemm(stream, hn, cWo, cWo, cWo, cbo, cbo, cbo,
                 qb, qb, qb, nullptr, 2048, 1024, 1024, 0, 0, 0, 1);
            add_shift_k<<<1922, 256, 0, stream>>>(qb, h);
        }

        // ---- FFW ----
        ln_k<<<2048, 256, 0, stream>>>(h, hn, ff_ln_s + p * 1024, ff_ln_b + p * 1024,
                                       nullptr, 0, 0);
        gemm(stream, hn, W1 + (size_t)p * 4 * MEG, W1 + (size_t)p * 4 * MEG,
             W1 + (size_t)p * 4 * MEG, b1 + p * 4096, b1 + p * 4096, b1 + p * 4096,
             ffh, ffh, ffh, nullptr, 2048, 4096, 1024, 1, 0, 0, 1);
        gemm(stream, ffh, W2 + (size_t)p * 4 * MEG, W2 + (size_t)p * 4 * MEG,
             W2 + (size_t)p * 4 * MEG, b2 + p * 1024, b2 + p * 1024, b2 + p * 1024,
             h, h, h, h /*residual*/, 2048, 1024, 4096, 0, 0, 0, 1);
    }

    // ---- LM head: (2048 x 1024) @ (1024 x 32000) ----
    gemm(stream, h, Wr, Wr, Wr, br, br, br, out, out, out, nullptr,
         2048, 32000, 1024, 0, 0, 0, 1);
}